// Round 5
// baseline (278.880 us; speedup 1.0000x reference)
//
#include <hip/hip_runtime.h>
#include <math.h>

#define NT 262144
#define KD 512
#define NE 64
#define DE 64

constexpr int BM = 128;       // tokens per block
constexpr int LA = 132;       // LDS stride for h_norm [d][tok]
constexpr int NS = KD / 32;   // 16 K-steps
constexpr int WS_EN = 49152;  // u32 offset of e_norm^T region in workspace

using f32x4 = __attribute__((ext_vector_type(4))) float;
using s16x8 = __attribute__((ext_vector_type(8))) short;

typedef const __attribute__((address_space(1))) unsigned int* gp1_t;
typedef __attribute__((address_space(3))) unsigned int* lp3_t;

// ---- 3-term truncated bf16 split of fp32: x = x1 + x2 + x3, |res| <= 2^-24|x| ----
__device__ __forceinline__ void split8(float4 lo, float4 hi,
                                       s16x8& o1, s16x8& o2, s16x8& o3) {
    float x[8] = {lo.x, lo.y, lo.z, lo.w, hi.x, hi.y, hi.z, hi.w};
    union { unsigned int u[4]; s16x8 v; } r1, r2, r3;
    #pragma unroll
    for (int p = 0; p < 4; ++p) {
        float f0 = x[2 * p], f1 = x[2 * p + 1];
        unsigned int a = __float_as_uint(f0), b = __float_as_uint(f1);
        unsigned int a1 = a & 0xFFFF0000u, b1 = b & 0xFFFF0000u;
        r1.u[p] = (a1 >> 16) | b1;
        float q0 = f0 - __uint_as_float(a1);
        float q1 = f1 - __uint_as_float(b1);
        unsigned int a2 = __float_as_uint(q0) & 0xFFFF0000u;
        unsigned int b2 = __float_as_uint(q1) & 0xFFFF0000u;
        r2.u[p] = (a2 >> 16) | b2;
        float s0 = q0 - __uint_as_float(a2);
        float s1 = q1 - __uint_as_float(b2);
        r3.u[p] = (__float_as_uint(s0) >> 16) | (__float_as_uint(s1) & 0xFFFF0000u);
    }
    o1 = r1.v; o2 = r2.v; o3 = r3.v;
}

__device__ __forceinline__ s16x8 ld_frag(const unsigned int* p) {
    union { uint4 q; s16x8 v; } u;
    u.q = *(const uint4*)p;
    return u.v;
}

// ---- prep: blocks 0..15 split W into plane-interleaved bf16 fragments;
//      block 16 writes e_norm^T fp32. ----
__global__ void prep(const float* __restrict__ W, const float* __restrict__ E,
                     unsigned int* __restrict__ ws) {
    const int tid = threadIdx.x;
    if (blockIdx.x < 16) {
        const int idx = blockIdx.x * 256 + tid;     // chunk: row*64 + k8
        const int row = idx >> 6, k8 = idx & 63;
        const float* src = W + (size_t)row * KD + k8 * 8;
        float4 lo = *(const float4*)src, hi = *(const float4*)(src + 4);
        s16x8 o1, o2, o3;
        split8(lo, hi, o1, o2, o3);
        union { s16x8 v; uint4 q; } u1, u2, u3;
        u1.v = o1; u2.v = o2; u3.v = o3;
        uint4* dst = (uint4*)(ws + (size_t)idx * 12);
        dst[0] = u1.q; dst[1] = u2.q; dst[2] = u3.q;
    } else {
        float* en = (float*)(ws + WS_EN);
        const int er = tid >> 2, part = tid & 3;
        float ss = 0.f;
        float4 ev[4];
        #pragma unroll
        for (int u = 0; u < 4; ++u) {
            ev[u] = *(const float4*)(E + er * DE + part * 16 + u * 4);
            ss = fmaf(ev[u].x, ev[u].x, ss);
            ss = fmaf(ev[u].y, ev[u].y, ss);
            ss = fmaf(ev[u].z, ev[u].z, ss);
            ss = fmaf(ev[u].w, ev[u].w, ss);
        }
        ss += __shfl_xor(ss, 1, 64);
        ss += __shfl_xor(ss, 2, 64);
        const float inv_e = 1.0f / fmaxf(sqrtf(ss), 1e-12f);
        #pragma unroll
        for (int u = 0; u < 4; ++u) {
            int d = part * 16 + u * 4;
            en[(d + 0) * 64 + er] = ev[u].x * inv_e;
            en[(d + 1) * 64 + er] = ev[u].y * inv_e;
            en[(d + 2) * 64 + er] = ev[u].z * inv_e;
            en[(d + 3) * 64 + er] = ev[u].w * inv_e;
        }
    }
}

// ---- fused main ----
// Stage-1: each wave stages ITS OWN 32-token A-slice (global_load_lds,
// XOR-pre-swizzled source, double-buffered LDS) and consumes only that slice
// -> NO block barriers, NO sched pins in the K-loop. Waves de-phase freely;
// per-wave ordering is just the counted vmcnt. B-operand: plane-interleaved
// bf16 W-splits (L2-hot), scheduled freely among the MFMAs.
__global__ __launch_bounds__(256, 4) void moe_all(const float* __restrict__ h,
                                                  const unsigned int* __restrict__ wsW,
                                                  const float* __restrict__ enorm,
                                                  const float* __restrict__ tau_p,
                                                  float* __restrict__ out) {
    // [0, 8192) : two 4096-float staging buffers; later h_norm [64][132] (8448)
    __shared__ float smem[DE * LA];

    const int tid = threadIdx.x;
    const int lane = tid & 63;
    const int wv = tid >> 6;          // wave 0..3 -> tokens [wv*32, wv*32+32)
    const int lr = lane & 15;         // fragment row/col within 16
    const int lk = lane >> 4;         // k-group 0..3
    const long tok0 = (long)blockIdx.x * BM;

    f32x4 acc[2][4];                  // [row-tile][col-tile], 16x16 each
    #pragma unroll
    for (int rt = 0; rt < 2; ++rt)
        #pragma unroll
        for (int ct = 0; ct < 4; ++ct)
            acc[rt][ct] = (f32x4){0.f, 0.f, 0.f, 0.f};

    // staging: wave wv writes rows wv*32..wv*32+31 (its own slice), lane->16B
#define STAGE_ISSUE(CUR, KS)                                                   \
    {                                                                          \
        _Pragma("unroll")                                                      \
        for (int n = 0; n < 4; ++n) {                                          \
            const int flat = (wv * 4 + n) * 64 + lane;                         \
            const int t = flat >> 3, q = flat & 7;                             \
            const int qs = q ^ (t & 7);                                        \
            const float* g = h + (tok0 + t) * (long)KD + (KS) * 32 + qs * 4;   \
            float* l = smem + (CUR) * 4096 + (wv * 4 + n) * 256;               \
            __builtin_amdgcn_global_load_lds((gp1_t)(const void*)g,            \
                                             (lp3_t)(void*)l, 16, 0, 0);       \
        }                                                                      \
    }

    STAGE_ISSUE(0, 0);

    const int tt0 = wv * 32 + lr;       // token rows this lane reads
    const int tt1 = tt0 + 16;
    const int sw = lr & 7;              // XOR key (same for tt0, tt1)
    const int q0 = (lk * 2) ^ sw;       // LDS quad holding global quad lk*2
    const int q1 = (lk * 2 + 1) ^ sw;

    for (int ks = 0; ks < NS; ++ks) {
        const int cur = ks & 1;
        if (ks + 1 < NS) {
            STAGE_ISSUE(cur ^ 1, ks + 1);
            // own stage(ks) resident (oldest 4 of <=8 outstanding); next in flight
            asm volatile("s_waitcnt vmcnt(4)" ::: "memory");
        } else {
            asm volatile("s_waitcnt vmcnt(0)" ::: "memory");
        }

        const float* base = smem + cur * 4096;
        float4 xl0 = *(const float4*)(base + tt0 * 32 + q0 * 4);
        float4 xh0 = *(const float4*)(base + tt0 * 32 + q1 * 4);
        float4 xl1 = *(const float4*)(base + tt1 * 32 + q0 * 4);
        float4 xh1 = *(const float4*)(base + tt1 * 32 + q1 * 4);

        s16x8 a1[2], a2[2], a3[2];
        split8(xl0, xh0, a1[0], a2[0], a3[0]);
        split8(xl1, xh1, a1[1], a2[1], a3[1]);

        const int k8 = ks * 4 + lk;
        #pragma unroll
        for (int ct = 0; ct < 4; ++ct) {
            const int bi = ((ct * 16 + lr) * 64 + k8) * 12;
            s16x8 b1 = ld_frag(wsW + bi);
            s16x8 b2 = ld_frag(wsW + bi + 4);
            s16x8 b3 = ld_frag(wsW + bi + 8);
            f32x4 c0 = acc[0][ct], c1 = acc[1][ct];
            c0 = __builtin_amdgcn_mfma_f32_16x16x32_bf16(a1[0], b1, c0, 0, 0, 0);
            c1 = __builtin_amdgcn_mfma_f32_16x16x32_bf16(a1[1], b1, c1, 0, 0, 0);
            c0 = __builtin_amdgcn_mfma_f32_16x16x32_bf16(a2[0], b1, c0, 0, 0, 0);
            c1 = __builtin_amdgcn_mfma_f32_16x16x32_bf16(a2[1], b1, c1, 0, 0, 0);
            c0 = __builtin_amdgcn_mfma_f32_16x16x32_bf16(a1[0], b2, c0, 0, 0, 0);
            c1 = __builtin_amdgcn_mfma_f32_16x16x32_bf16(a1[1], b2, c1, 0, 0, 0);
            c0 = __builtin_amdgcn_mfma_f32_16x16x32_bf16(a3[0], b1, c0, 0, 0, 0);
            c1 = __builtin_amdgcn_mfma_f32_16x16x32_bf16(a3[1], b1, c1, 0, 0, 0);
            c0 = __builtin_amdgcn_mfma_f32_16x16x32_bf16(a2[0], b2, c0, 0, 0, 0);
            c1 = __builtin_amdgcn_mfma_f32_16x16x32_bf16(a2[1], b2, c1, 0, 0, 0);
            c0 = __builtin_amdgcn_mfma_f32_16x16x32_bf16(a1[0], b3, c0, 0, 0, 0);
            c1 = __builtin_amdgcn_mfma_f32_16x16x32_bf16(a1[1], b3, c1, 0, 0, 0);
            acc[0][ct] = c0; acc[1][ct] = c1;
        }
    }

    // ---- per-token L2 norm from fragments ----
    // C/D layout: col = lane&15 (d), row = (lane>>4)*4 + reg (token within 16)
    float inv_n[2][4];
    #pragma unroll
    for (int rt = 0; rt < 2; ++rt) {
        #pragma unroll
        for (int r = 0; r < 4; ++r) {
            float ss = 0.f;
            #pragma unroll
            for (int ct = 0; ct < 4; ++ct)
                ss = fmaf(acc[rt][ct][r], acc[rt][ct][r], ss);
            ss += __shfl_xor(ss, 1, 64);
            ss += __shfl_xor(ss, 2, 64);
            ss += __shfl_xor(ss, 4, 64);
            ss += __shfl_xor(ss, 8, 64);
            inv_n[rt][r] = 1.0f / fmaxf(sqrtf(ss), 1e-12f);
        }
    }

    __syncthreads();   // all waves done reading staging buffers (h_norm overlays them)

    // h_norm -> smem as [d][tok]
    #pragma unroll
    for (int rt = 0; rt < 2; ++rt)
        #pragma unroll
        for (int ct = 0; ct < 4; ++ct)
            #pragma unroll
            for (int r = 0; r < 4; ++r) {
                const int d = ct * 16 + lr;
                const int t = wv * 32 + rt * 16 + lk * 4 + r;
                smem[d * LA + t] = acc[rt][ct][r] * inv_n[rt][r];
            }
    __syncthreads();   // h_norm visible to all

    // ---- stage 2: scores[128][64] = h_norm @ e_norm^T (K=64), fp32 VALU ----
    const int tx = tid & 15;   // cols tx*4 + j
    const int ty = tid >> 4;   // tokens p*64 + ty*4 + i
    float sacc[2][4][4];
    #pragma unroll
    for (int p = 0; p < 2; ++p)
        #pragma unroll
        for (int i = 0; i < 4; ++i)
            #pragma unroll
            for (int j = 0; j < 4; ++j) sacc[p][i][j] = 0.0f;

    #pragma unroll 8
    for (int dd = 0; dd < DE; ++dd) {
        const float* ra = smem + dd * LA;
        float4 a0 = *(const float4*)(ra + ty * 4);
        float4 a1v = *(const float4*)(ra + 64 + ty * 4);
        float4 b  = *(const float4*)(enorm + dd * 64 + tx * 4);
        float av[2][4] = {{a0.x, a0.y, a0.z, a0.w}, {a1v.x, a1v.y, a1v.z, a1v.w}};
        float bv[4] = {b.x, b.y, b.z, b.w};
        #pragma unroll
        for (int p = 0; p < 2; ++p)
            #pragma unroll
            for (int i = 0; i < 4; ++i)
                #pragma unroll
                for (int j = 0; j < 4; ++j)
                    sacc[p][i][j] = fmaf(av[p][i], bv[j], sacc[p][i][j]);
    }

    // ---- epilogue: softmax, top-2, outputs ----
    const float inv_tau = 1.0f / tau_p[0];
    float* outS = out;                        // sparse_gates [NT][64]
    float* outI = out + (size_t)NT * 64;      // topk_indices [NT][2] (as float)
    float* outF = out + (size_t)NT * 66;      // full_gates   [NT][64]

    #pragma unroll
    for (int p = 0; p < 2; ++p) {
        #pragma unroll
        for (int i = 0; i < 4; ++i) {
            const long tok = tok0 + p * 64 + ty * 4 + i;
            float s[4];
            #pragma unroll
            for (int j = 0; j < 4; ++j) s[j] = sacc[p][i][j] * inv_tau;

            float m = fmaxf(fmaxf(s[0], s[1]), fmaxf(s[2], s[3]));
            m = fmaxf(m, __shfl_xor(m, 1, 64));
            m = fmaxf(m, __shfl_xor(m, 2, 64));
            m = fmaxf(m, __shfl_xor(m, 4, 64));
            m = fmaxf(m, __shfl_xor(m, 8, 64));

            float g[4], z = 0.f;
            #pragma unroll
            for (int j = 0; j < 4; ++j) { g[j] = __expf(s[j] - m); z += g[j]; }
            z += __shfl_xor(z, 1, 64);
            z += __shfl_xor(z, 2, 64);
            z += __shfl_xor(z, 4, 64);
            z += __shfl_xor(z, 8, 64);
            const float invZ = 1.0f / z;

            *(float4*)(outF + tok * 64 + tx * 4) =
                make_float4(g[0] * invZ, g[1] * invZ, g[2] * invZ, g[3] * invZ);

            // top-2 on s (monotone with gates); ties -> lower index (jax top_k)
            float v1 = -3.4e38f, v2 = -3.4e38f;
            int i1 = 1 << 20, i2 = 1 << 20;
            #pragma unroll
            for (int j = 0; j < 4; ++j) {
                float v = s[j];
                int e = tx * 4 + j;
                if (v > v1 || (v == v1 && e < i1)) { v2 = v1; i2 = i1; v1 = v; i1 = e; }
                else if (v > v2 || (v == v2 && e < i2)) { v2 = v; i2 = e; }
            }
            #pragma unroll
            for (int msk = 1; msk <= 8; msk <<= 1) {
                float o1 = __shfl_xor(v1, msk, 64); int oi1 = __shfl_xor(i1, msk, 64);
                float o2 = __shfl_xor(v2, msk, 64); int oi2 = __shfl_xor(i2, msk, 64);
                if (o1 > v1 || (o1 == v1 && oi1 < i1)) {
                    if (v1 > o2 || (v1 == o2 && i1 < oi2)) { v2 = v1; i2 = i1; }
                    else { v2 = o2; i2 = oi2; }
                    v1 = o1; i1 = oi1;
                } else {
                    if (o1 > v2 || (o1 == v2 && oi1 < i2)) { v2 = o1; i2 = oi1; }
                }
            }

            // softmax over the two top GATE values
            float gv1 = __expf(v1 - m) * invZ;
            float gv2 = __expf(v2 - m) * invZ;
            float qq = __expf(gv2 - gv1);
            float w1 = 1.0f / (1.0f + qq);
            float w2 = qq * w1;

            float sp[4];
            #pragma unroll
            for (int j = 0; j < 4; ++j) {
                int e = tx * 4 + j;
                sp[j] = (e == i1) ? w1 : ((e == i2) ? w2 : 0.0f);
            }
            *(float4*)(outS + tok * 64 + tx * 4) = make_float4(sp[0], sp[1], sp[2], sp[3]);
            if (tx == 0) {
                *(float2*)(outI + tok * 2) = make_float2((float)i1, (float)i2);
            }
        }
    }
#undef STAGE_ISSUE
}

extern "C" void kernel_launch(void* const* d_in, const int* in_sizes, int n_in,
                              void* d_out, int out_size, void* d_ws, size_t ws_size,
                              hipStream_t stream) {
    const float* h   = (const float*)d_in[0];
    const float* W   = (const float*)d_in[1];
    const float* E   = (const float*)d_in[2];
    const float* tau = (const float*)d_in[3];
    float* out = (float*)d_out;
    unsigned int* ws = (unsigned int*)d_ws;   // 192KB W frags + 16KB e_norm^T

    prep<<<17, 256, 0, stream>>>(W, E, ws);
    moe_all<<<NT / BM, 256, 0, stream>>>(h, ws, (const float*)(ws + WS_EN), tau, out);
}

// Round 6
// 217.873 us; speedup vs baseline: 1.2800x; 1.2800x over previous
//
#include <hip/hip_runtime.h>
#include <math.h>

#define NT 262144
#define KD 512
#define NE 64
#define DE 64

constexpr int BM = 128;       // tokens per block
constexpr int LA = 132;       // LDS stride for h_norm [d][tok]
constexpr int NS = KD / 32;   // 16 K-steps
constexpr int WS_EN = 49152;  // u32 offset of e_norm^T region in workspace

using f32x4 = __attribute__((ext_vector_type(4))) float;
using s16x8 = __attribute__((ext_vector_type(8))) short;

typedef const __attribute__((address_space(1))) unsigned int* gp1_t;
typedef __attribute__((address_space(3))) unsigned int* lp3_t;

// ---- 3-term truncated bf16 split of fp32: x = x1 + x2 + x3, |res| <= 2^-24|x| ----
__device__ __forceinline__ void split8(float4 lo, float4 hi,
                                       s16x8& o1, s16x8& o2, s16x8& o3) {
    float x[8] = {lo.x, lo.y, lo.z, lo.w, hi.x, hi.y, hi.z, hi.w};
    union { unsigned int u[4]; s16x8 v; } r1, r2, r3;
    #pragma unroll
    for (int p = 0; p < 4; ++p) {
        float f0 = x[2 * p], f1 = x[2 * p + 1];
        unsigned int a = __float_as_uint(f0), b = __float_as_uint(f1);
        unsigned int a1 = a & 0xFFFF0000u, b1 = b & 0xFFFF0000u;
        r1.u[p] = (a1 >> 16) | b1;
        float q0 = f0 - __uint_as_float(a1);
        float q1 = f1 - __uint_as_float(b1);
        unsigned int a2 = __float_as_uint(q0) & 0xFFFF0000u;
        unsigned int b2 = __float_as_uint(q1) & 0xFFFF0000u;
        r2.u[p] = (a2 >> 16) | b2;
        float s0 = q0 - __uint_as_float(a2);
        float s1 = q1 - __uint_as_float(b2);
        r3.u[p] = (__float_as_uint(s0) >> 16) | (__float_as_uint(s1) & 0xFFFF0000u);
    }
    o1 = r1.v; o2 = r2.v; o3 = r3.v;
}

__device__ __forceinline__ s16x8 ld_frag(const unsigned int* p) {
    union { uint4 q; s16x8 v; } u;
    u.q = *(const uint4*)p;
    return u.v;
}

// ---- prep: blocks 0..15 split W into FRAGMENT-ORDER bf16 planes;
//      block 16 writes e_norm^T fp32.
// W region layout (u32): group g = ks*4 + ct (64 groups); within a group,
// 3 planes x 64 lanes x 4 u32 (768 u32 = 3KB). Lane l of the MFMA B-fragment
// for (g, plane) reads u32s [g*768 + plane*256 + l*4 .. +4) -- each B-load
// instruction in the main kernel covers one CONTIGUOUS fully-used 1KB block.
__global__ void prep(const float* __restrict__ W, const float* __restrict__ E,
                     unsigned int* __restrict__ ws) {
    const int tid = threadIdx.x;
    if (blockIdx.x < 16) {
        const int idx = blockIdx.x * 256 + tid;     // chunk: row*64 + k8
        const int row = idx >> 6, k8 = idx & 63;
        const float* src = W + (size_t)row * KD + k8 * 8;
        float4 lo = *(const float4*)src, hi = *(const float4*)(src + 4);
        s16x8 o1, o2, o3;
        split8(lo, hi, o1, o2, o3);
        union { s16x8 v; uint4 q; } u1, u2, u3;
        u1.v = o1; u2.v = o2; u3.v = o3;
        const int ks = k8 >> 2, lk = k8 & 3, ct = row >> 4, lr = row & 15;
        const int g = ks * 4 + ct, lane = lk * 16 + lr;
        unsigned int* base = ws + (size_t)g * 768 + lane * 4;
        *(uint4*)(base)       = u1.q;
        *(uint4*)(base + 256) = u2.q;
        *(uint4*)(base + 512) = u3.q;
    } else {
        float* en = (float*)(ws + WS_EN);
        const int er = tid >> 2, part = tid & 3;
        float ss = 0.f;
        float4 ev[4];
        #pragma unroll
        for (int u = 0; u < 4; ++u) {
            ev[u] = *(const float4*)(E + er * DE + part * 16 + u * 4);
            ss = fmaf(ev[u].x, ev[u].x, ss);
            ss = fmaf(ev[u].y, ev[u].y, ss);
            ss = fmaf(ev[u].z, ev[u].z, ss);
            ss = fmaf(ev[u].w, ev[u].w, ss);
        }
        ss += __shfl_xor(ss, 1, 64);
        ss += __shfl_xor(ss, 2, 64);
        const float inv_e = 1.0f / fmaxf(sqrtf(ss), 1e-12f);
        #pragma unroll
        for (int u = 0; u < 4; ++u) {
            int d = part * 16 + u * 4;
            en[(d + 0) * 64 + er] = ev[u].x * inv_e;
            en[(d + 1) * 64 + er] = ev[u].y * inv_e;
            en[(d + 2) * 64 + er] = ev[u].z * inv_e;
            en[(d + 3) * 64 + er] = ev[u].w * inv_e;
        }
    }
}

// ---- fused main ----
// Stage-1: each wave stages ITS OWN 32-token A-slice (global_load_lds,
// XOR-pre-swizzled source, double-buffered LDS), no block barriers in the
// K-loop. B-operand: fragment-order bf16 W-splits -- every B-load inst is a
// contiguous 1KB read (coalescing minimum; the old row-strided layout touched
// ~48 cache lines per inst and bound the kernel on the L1/TA request path).
__global__ __launch_bounds__(256, 4) void moe_all(const float* __restrict__ h,
                                                  const unsigned int* __restrict__ wsW,
                                                  const float* __restrict__ enorm,
                                                  const float* __restrict__ tau_p,
                                                  float* __restrict__ out) {
    // [0, 8192) : two 4096-float staging buffers; later h_norm [64][132] (8448)
    __shared__ float smem[DE * LA];

    const int tid = threadIdx.x;
    const int lane = tid & 63;
    const int wv = tid >> 6;          // wave 0..3 -> tokens [wv*32, wv*32+32)
    const int lr = lane & 15;         // fragment row/col within 16
    const int lk = lane >> 4;         // k-group 0..3
    const long tok0 = (long)blockIdx.x * BM;

    f32x4 acc[2][4];                  // [row-tile][col-tile], 16x16 each
    #pragma unroll
    for (int rt = 0; rt < 2; ++rt)
        #pragma unroll
        for (int ct = 0; ct < 4; ++ct)
            acc[rt][ct] = (f32x4){0.f, 0.f, 0.f, 0.f};

    // staging: wave wv writes rows wv*32..wv*32+31 (its own slice), lane->16B
#define STAGE_ISSUE(CUR, KS)                                                   \
    {                                                                          \
        _Pragma("unroll")                                                      \
        for (int n = 0; n < 4; ++n) {                                          \
            const int flat = (wv * 4 + n) * 64 + lane;                         \
            const int t = flat >> 3, q = flat & 7;                             \
            const int qs = q ^ (t & 7);                                        \
            const float* g = h + (tok0 + t) * (long)KD + (KS) * 32 + qs * 4;   \
            float* l = smem + (CUR) * 4096 + (wv * 4 + n) * 256;               \
            __builtin_amdgcn_global_load_lds((gp1_t)(const void*)g,            \
                                             (lp3_t)(void*)l, 16, 0, 0);       \
        }                                                                      \
    }

    STAGE_ISSUE(0, 0);

    const int tt0 = wv * 32 + lr;       // token rows this lane reads
    const int tt1 = tt0 + 16;
    const int sw = lr & 7;              // XOR key (same for tt0, tt1)
    const int q0 = (lk * 2) ^ sw;       // LDS quad holding global quad lk*2
    const int q1 = (lk * 2 + 1) ^ sw;

    for (int ks = 0; ks < NS; ++ks) {
        const int cur = ks & 1;
        if (ks + 1 < NS) {
            STAGE_ISSUE(cur ^ 1, ks + 1);
            // own stage(ks) resident (oldest 4 of <=8 outstanding); next in flight
            asm volatile("s_waitcnt vmcnt(4)" ::: "memory");
        } else {
            asm volatile("s_waitcnt vmcnt(0)" ::: "memory");
        }

        const float* base = smem + cur * 4096;
        float4 xl0 = *(const float4*)(base + tt0 * 32 + q0 * 4);
        float4 xh0 = *(const float4*)(base + tt0 * 32 + q1 * 4);
        float4 xl1 = *(const float4*)(base + tt1 * 32 + q0 * 4);
        float4 xh1 = *(const float4*)(base + tt1 * 32 + q1 * 4);

        s16x8 a1[2], a2[2], a3[2];
        split8(xl0, xh0, a1[0], a2[0], a3[0]);
        split8(xl1, xh1, a1[1], a2[1], a3[1]);

        #pragma unroll
        for (int ct = 0; ct < 4; ++ct) {
            const int bi = (ks * 4 + ct) * 768 + lane * 4;   // u32 index
            s16x8 b1 = ld_frag(wsW + bi);
            s16x8 b2 = ld_frag(wsW + bi + 256);
            s16x8 b3 = ld_frag(wsW + bi + 512);
            f32x4 c0 = acc[0][ct], c1 = acc[1][ct];
            c0 = __builtin_amdgcn_mfma_f32_16x16x32_bf16(a1[0], b1, c0, 0, 0, 0);
            c1 = __builtin_amdgcn_mfma_f32_16x16x32_bf16(a1[1], b1, c1, 0, 0, 0);
            c0 = __builtin_amdgcn_mfma_f32_16x16x32_bf16(a2[0], b1, c0, 0, 0, 0);
            c1 = __builtin_amdgcn_mfma_f32_16x16x32_bf16(a2[1], b1, c1, 0, 0, 0);
            c0 = __builtin_amdgcn_mfma_f32_16x16x32_bf16(a1[0], b2, c0, 0, 0, 0);
            c1 = __builtin_amdgcn_mfma_f32_16x16x32_bf16(a1[1], b2, c1, 0, 0, 0);
            c0 = __builtin_amdgcn_mfma_f32_16x16x32_bf16(a3[0], b1, c0, 0, 0, 0);
            c1 = __builtin_amdgcn_mfma_f32_16x16x32_bf16(a3[1], b1, c1, 0, 0, 0);
            c0 = __builtin_amdgcn_mfma_f32_16x16x32_bf16(a2[0], b2, c0, 0, 0, 0);
            c1 = __builtin_amdgcn_mfma_f32_16x16x32_bf16(a2[1], b2, c1, 0, 0, 0);
            c0 = __builtin_amdgcn_mfma_f32_16x16x32_bf16(a1[0], b3, c0, 0, 0, 0);
            c1 = __builtin_amdgcn_mfma_f32_16x16x32_bf16(a1[1], b3, c1, 0, 0, 0);
            acc[0][ct] = c0; acc[1][ct] = c1;
        }
    }

    // ---- per-token L2 norm from fragments ----
    // C/D layout: col = lane&15 (d), row = (lane>>4)*4 + reg (token within 16)
    float inv_n[2][4];
    #pragma unroll
    for (int rt = 0; rt < 2; ++rt) {
        #pragma unroll
        for (int r = 0; r < 4; ++r) {
            float ss = 0.f;
            #pragma unroll
            for (int ct = 0; ct < 4; ++ct)
                ss = fmaf(acc[rt][ct][r], acc[rt][ct][r], ss);
            ss += __shfl_xor(ss, 1, 64);
            ss += __shfl_xor(ss, 2, 64);
            ss += __shfl_xor(ss, 4, 64);
            ss += __shfl_xor(ss, 8, 64);
            inv_n[rt][r] = 1.0f / fmaxf(sqrtf(ss), 1e-12f);
        }
    }

    __syncthreads();   // all waves done reading staging buffers (h_norm overlays them)

    // h_norm -> smem as [d][tok]
    #pragma unroll
    for (int rt = 0; rt < 2; ++rt)
        #pragma unroll
        for (int ct = 0; ct < 4; ++ct)
            #pragma unroll
            for (int r = 0; r < 4; ++r) {
                const int d = ct * 16 + lr;
                const int t = wv * 32 + rt * 16 + lk * 4 + r;
                smem[d * LA + t] = acc[rt][ct][r] * inv_n[rt][r];
            }
    __syncthreads();   // h_norm visible to all

    // ---- stage 2: scores[128][64] = h_norm @ e_norm^T (K=64), fp32 VALU ----
    const int tx = tid & 15;   // cols tx*4 + j
    const int ty = tid >> 4;   // tokens p*64 + ty*4 + i
    float sacc[2][4][4];
    #pragma unroll
    for (int p = 0; p < 2; ++p)
        #pragma unroll
        for (int i = 0; i < 4; ++i)
            #pragma unroll
            for (int j = 0; j < 4; ++j) sacc[p][i][j] = 0.0f;

    #pragma unroll 8
    for (int dd = 0; dd < DE; ++dd) {
        const float* ra = smem + dd * LA;
        float4 a0 = *(const float4*)(ra + ty * 4);
        float4 a1v = *(const float4*)(ra + 64 + ty * 4);
        float4 b  = *(const float4*)(enorm + dd * 64 + tx * 4);
        float av[2][4] = {{a0.x, a0.y, a0.z, a0.w}, {a1v.x, a1v.y, a1v.z, a1v.w}};
        float bv[4] = {b.x, b.y, b.z, b.w};
        #pragma unroll
        for (int p = 0; p < 2; ++p)
            #pragma unroll
            for (int i = 0; i < 4; ++i)
                #pragma unroll
                for (int j = 0; j < 4; ++j)
                    sacc[p][i][j] = fmaf(av[p][i], bv[j], sacc[p][i][j]);
    }

    // ---- epilogue: softmax, top-2, outputs ----
    const float inv_tau = 1.0f / tau_p[0];
    float* outS = out;                        // sparse_gates [NT][64]
    float* outI = out + (size_t)NT * 64;      // topk_indices [NT][2] (as float)
    float* outF = out + (size_t)NT * 66;      // full_gates   [NT][64]

    #pragma unroll
    for (int p = 0; p < 2; ++p) {
        #pragma unroll
        for (int i = 0; i < 4; ++i) {
            const long tok = tok0 + p * 64 + ty * 4 + i;
            float s[4];
            #pragma unroll
            for (int j = 0; j < 4; ++j) s[j] = sacc[p][i][j] * inv_tau;

            float m = fmaxf(fmaxf(s[0], s[1]), fmaxf(s[2], s[3]));
            m = fmaxf(m, __shfl_xor(m, 1, 64));
            m = fmaxf(m, __shfl_xor(m, 2, 64));
            m = fmaxf(m, __shfl_xor(m, 4, 64));
            m = fmaxf(m, __shfl_xor(m, 8, 64));

            float g[4], z = 0.f;
            #pragma unroll
            for (int j = 0; j < 4; ++j) { g[j] = __expf(s[j] - m); z += g[j]; }
            z += __shfl_xor(z, 1, 64);
            z += __shfl_xor(z, 2, 64);
            z += __shfl_xor(z, 4, 64);
            z += __shfl_xor(z, 8, 64);
            const float invZ = 1.0f / z;

            *(float4*)(outF + tok * 64 + tx * 4) =
                make_float4(g[0] * invZ, g[1] * invZ, g[2] * invZ, g[3] * invZ);

            // top-2 on s (monotone with gates); ties -> lower index (jax top_k)
            float v1 = -3.4e38f, v2 = -3.4e38f;
            int i1 = 1 << 20, i2 = 1 << 20;
            #pragma unroll
            for (int j = 0; j < 4; ++j) {
                float v = s[j];
                int e = tx * 4 + j;
                if (v > v1 || (v == v1 && e < i1)) { v2 = v1; i2 = i1; v1 = v; i1 = e; }
                else if (v > v2 || (v == v2 && e < i2)) { v2 = v; i2 = e; }
            }
            #pragma unroll
            for (int msk = 1; msk <= 8; msk <<= 1) {
                float o1 = __shfl_xor(v1, msk, 64); int oi1 = __shfl_xor(i1, msk, 64);
                float o2 = __shfl_xor(v2, msk, 64); int oi2 = __shfl_xor(i2, msk, 64);
                if (o1 > v1 || (o1 == v1 && oi1 < i1)) {
                    if (v1 > o2 || (v1 == o2 && i1 < oi2)) { v2 = v1; i2 = i1; }
                    else { v2 = o2; i2 = oi2; }
                    v1 = o1; i1 = oi1;
                } else {
                    if (o1 > v2 || (o1 == v2 && oi1 < i2)) { v2 = o1; i2 = oi1; }
                }
            }

            // softmax over the two top GATE values
            float gv1 = __expf(v1 - m) * invZ;
            float gv2 = __expf(v2 - m) * invZ;
            float qq = __expf(gv2 - gv1);
            float w1 = 1.0f / (1.0f + qq);
            float w2 = qq * w1;

            float sp[4];
            #pragma unroll
            for (int j = 0; j < 4; ++j) {
                int e = tx * 4 + j;
                sp[j] = (e == i1) ? w1 : ((e == i2) ? w2 : 0.0f);
            }
            *(float4*)(outS + tok * 64 + tx * 4) = make_float4(sp[0], sp[1], sp[2], sp[3]);
            if (tx == 0) {
                *(float2*)(outI + tok * 2) = make_float2((float)i1, (float)i2);
            }
        }
    }
#undef STAGE_ISSUE
}

extern "C" void kernel_launch(void* const* d_in, const int* in_sizes, int n_in,
                              void* d_out, int out_size, void* d_ws, size_t ws_size,
                              hipStream_t stream) {
    const float* h   = (const float*)d_in[0];
    const float* W   = (const float*)d_in[1];
    const float* E   = (const float*)d_in[2];
    const float* tau = (const float*)d_in[3];
    float* out = (float*)d_out;
    unsigned int* ws = (unsigned int*)d_ws;   // 192KB W frags + 16KB e_norm^T

    prep<<<17, 256, 0, stream>>>(W, E, ws);
    moe_all<<<NT / BM, 256, 0, stream>>>(h, ws, (const float*)(ws + WS_EN), tau, out);
}

// Round 7
// 191.205 us; speedup vs baseline: 1.4585x; 1.1395x over previous
//
#include <hip/hip_runtime.h>
#include <math.h>

#define NT 262144
#define KD 512
#define NE 64
#define DE 64

constexpr int BM = 128;       // tokens per block
constexpr int LA = 132;       // LDS stride for h_norm [d][tok]
constexpr int NS = KD / 32;   // 16 K-steps
constexpr int WS_EN = 49152;  // u32 offset of e_norm^T region in workspace

using f32x4 = __attribute__((ext_vector_type(4))) float;
using s16x8 = __attribute__((ext_vector_type(8))) short;

typedef const __attribute__((address_space(1))) unsigned int* gp1_t;
typedef __attribute__((address_space(3))) unsigned int* lp3_t;

// ---- 3-term truncated bf16 split of fp32: x = x1 + x2 + x3, |res| <= 2^-24|x| ----
__device__ __forceinline__ void split8(float4 lo, float4 hi,
                                       s16x8& o1, s16x8& o2, s16x8& o3) {
    float x[8] = {lo.x, lo.y, lo.z, lo.w, hi.x, hi.y, hi.z, hi.w};
    union { unsigned int u[4]; s16x8 v; } r1, r2, r3;
    #pragma unroll
    for (int p = 0; p < 4; ++p) {
        float f0 = x[2 * p], f1 = x[2 * p + 1];
        unsigned int a = __float_as_uint(f0), b = __float_as_uint(f1);
        unsigned int a1 = a & 0xFFFF0000u, b1 = b & 0xFFFF0000u;
        r1.u[p] = (a1 >> 16) | b1;
        float q0 = f0 - __uint_as_float(a1);
        float q1 = f1 - __uint_as_float(b1);
        unsigned int a2 = __float_as_uint(q0) & 0xFFFF0000u;
        unsigned int b2 = __float_as_uint(q1) & 0xFFFF0000u;
        r2.u[p] = (a2 >> 16) | b2;
        float s0 = q0 - __uint_as_float(a2);
        float s1 = q1 - __uint_as_float(b2);
        r3.u[p] = (__float_as_uint(s0) >> 16) | (__float_as_uint(s1) & 0xFFFF0000u);
    }
    o1 = r1.v; o2 = r2.v; o3 = r3.v;
}

__device__ __forceinline__ s16x8 ld_frag(const unsigned int* p) {
    union { uint4 q; s16x8 v; } u;
    u.q = *(const uint4*)p;
    return u.v;
}

// ---- prep: blocks 0..15 split W into FRAGMENT-ORDER bf16 planes;
//      block 16 writes e_norm^T fp32.
// W region layout (u32): group g = ks*4 + ct (64 groups); within a group,
// 3 planes x 64 lanes x 4 u32 (768 u32 = 3KB). One K-step = 4 groups = 12KB
// contiguous -- exactly what the main kernel DMA-stages per step.
__global__ void prep(const float* __restrict__ W, const float* __restrict__ E,
                     unsigned int* __restrict__ ws) {
    const int tid = threadIdx.x;
    if (blockIdx.x < 16) {
        const int idx = blockIdx.x * 256 + tid;     // chunk: row*64 + k8
        const int row = idx >> 6, k8 = idx & 63;
        const float* src = W + (size_t)row * KD + k8 * 8;
        float4 lo = *(const float4*)src, hi = *(const float4*)(src + 4);
        s16x8 o1, o2, o3;
        split8(lo, hi, o1, o2, o3);
        union { s16x8 v; uint4 q; } u1, u2, u3;
        u1.v = o1; u2.v = o2; u3.v = o3;
        const int ks = k8 >> 2, lk = k8 & 3, ct = row >> 4, lr = row & 15;
        const int g = ks * 4 + ct, lane = lk * 16 + lr;
        unsigned int* base = ws + (size_t)g * 768 + lane * 4;
        *(uint4*)(base)       = u1.q;
        *(uint4*)(base + 256) = u2.q;
        *(uint4*)(base + 512) = u3.q;
    } else {
        float* en = (float*)(ws + WS_EN);
        const int er = tid >> 2, part = tid & 3;
        float ss = 0.f;
        float4 ev[4];
        #pragma unroll
        for (int u = 0; u < 4; ++u) {
            ev[u] = *(const float4*)(E + er * DE + part * 16 + u * 4);
            ss = fmaf(ev[u].x, ev[u].x, ss);
            ss = fmaf(ev[u].y, ev[u].y, ss);
            ss = fmaf(ev[u].z, ev[u].z, ss);
            ss = fmaf(ev[u].w, ev[u].w, ss);
        }
        ss += __shfl_xor(ss, 1, 64);
        ss += __shfl_xor(ss, 2, 64);
        const float inv_e = 1.0f / fmaxf(sqrtf(ss), 1e-12f);
        #pragma unroll
        for (int u = 0; u < 4; ++u) {
            int d = part * 16 + u * 4;
            en[(d + 0) * 64 + er] = ev[u].x * inv_e;
            en[(d + 1) * 64 + er] = ev[u].y * inv_e;
            en[(d + 2) * 64 + er] = ev[u].z * inv_e;
            en[(d + 3) * 64 + er] = ev[u].w * inv_e;
        }
    }
}

// ---- fused main ----
// B-operand now staged through LDS ONCE PER BLOCK per K-step (12KB DMA,
// double-buffered) instead of 4 waves each loading identical fragments from
// L2 (W's 208KB never fits L1 -> every load was an L2 round-trip; that was
// ~40% of the wall). A-operand: per-wave LDS slice, single-buffered (re-DMA
// after own lgkmcnt). One s_barrier + vmcnt(0) per step; DMAs issue early in
// step k and are awaited at top of k+1 (~full-step hiding).
// LDS: [0,6144) B dbuf (24KB) | [6144,10240) A slices (16KB) -> 40KB, 4 blk/CU.
__global__ __launch_bounds__(256, 4) void moe_all(const float* __restrict__ h,
                                                  const unsigned int* __restrict__ wsW,
                                                  const float* __restrict__ enorm,
                                                  const float* __restrict__ tau_p,
                                                  float* __restrict__ out) {
    __shared__ float smem[10240];   // h_norm [64][132] (8448) overlays after stage-1

    const int tid = threadIdx.x;
    const int lane = tid & 63;
    const int wv = tid >> 6;          // wave 0..3 -> tokens [wv*32, wv*32+32)
    const int lr = lane & 15;         // fragment row/col within 16
    const int lk = lane >> 4;         // k-group 0..3
    const long tok0 = (long)blockIdx.x * BM;

    f32x4 acc[2][4];                  // [row-tile][col-tile], 16x16 each
    #pragma unroll
    for (int rt = 0; rt < 2; ++rt)
        #pragma unroll
        for (int ct = 0; ct < 4; ++ct)
            acc[rt][ct] = (f32x4){0.f, 0.f, 0.f, 0.f};

    // A: wave wv stages its own 32-token slice (4KB), XOR-pre-swizzled source
#define STAGE_A(KS)                                                            \
    {                                                                          \
        _Pragma("unroll")                                                      \
        for (int n = 0; n < 4; ++n) {                                          \
            const int flat = (wv * 4 + n) * 64 + lane;                         \
            const int t = flat >> 3, q = flat & 7;                             \
            const int qs = q ^ (t & 7);                                        \
            const float* g = h + (tok0 + t) * (long)KD + (KS) * 32 + qs * 4;   \
            float* l = smem + 6144 + wv * 1024 + n * 256;                      \
            __builtin_amdgcn_global_load_lds((gp1_t)(const void*)g,            \
                                             (lp3_t)(void*)l, 16, 0, 0);       \
        }                                                                      \
    }

    // B: whole block cooperatively copies step KS's 12KB (linear, lane*16B)
#define STAGE_B(CUR, KS)                                                       \
    {                                                                          \
        _Pragma("unroll")                                                      \
        for (int i = 0; i < 3; ++i) {                                          \
            const unsigned int* g = wsW + (size_t)(KS) * 3072 + i * 1024       \
                                    + wv * 256 + lane * 4;                     \
            float* l = smem + (CUR) * 3072 + i * 1024 + wv * 256;              \
            __builtin_amdgcn_global_load_lds((gp1_t)(const void*)g,            \
                                             (lp3_t)(void*)l, 16, 0, 0);       \
        }                                                                      \
    }

    STAGE_B(0, 0);
    STAGE_A(0);

    const int sw = lr & 7;              // XOR key (rows lr and lr+16 share it)
    const int q0 = (lk * 2) ^ sw;       // LDS quad holding global quad lk*2
    const int q1 = (lk * 2 + 1) ^ sw;
    const float* abase = smem + 6144 + wv * 1024;

    for (int ks = 0; ks < NS; ++ks) {
        const int cur = ks & 1;
        // own 7 DMAs (A[ks] + share of B[cur]) outstanding -> drain
        asm volatile("s_waitcnt vmcnt(0)" ::: "memory");
        __builtin_amdgcn_s_barrier();   // everyone's B[cur] landed; B[cur^1]
                                        // reads (step ks-1) all complete
        if (ks + 1 < NS) { STAGE_B(cur ^ 1, ks + 1); }
        __builtin_amdgcn_sched_barrier(0);

        float4 xl0 = *(const float4*)(abase + lr * 32 + q0 * 4);
        float4 xh0 = *(const float4*)(abase + lr * 32 + q1 * 4);
        float4 xl1 = *(const float4*)(abase + (lr + 16) * 32 + q0 * 4);
        float4 xh1 = *(const float4*)(abase + (lr + 16) * 32 + q1 * 4);
        asm volatile("s_waitcnt lgkmcnt(0)" ::: "memory");  // A regs ready -> buf free
        if (ks + 1 < NS) { STAGE_A(ks + 1); }               // reuse single A buf
        __builtin_amdgcn_sched_barrier(0);

        s16x8 a1[2], a2[2], a3[2];
        split8(xl0, xh0, a1[0], a2[0], a3[0]);
        split8(xl1, xh1, a1[1], a2[1], a3[1]);

        #pragma unroll
        for (int ct = 0; ct < 4; ++ct) {
            const unsigned int* bb =
                (const unsigned int*)(smem + cur * 3072 + ct * 768) + lane * 4;
            s16x8 b1 = ld_frag(bb);
            s16x8 b2 = ld_frag(bb + 256);
            s16x8 b3 = ld_frag(bb + 512);
            f32x4 c0 = acc[0][ct], c1 = acc[1][ct];
            c0 = __builtin_amdgcn_mfma_f32_16x16x32_bf16(a1[0], b1, c0, 0, 0, 0);
            c1 = __builtin_amdgcn_mfma_f32_16x16x32_bf16(a1[1], b1, c1, 0, 0, 0);
            c0 = __builtin_amdgcn_mfma_f32_16x16x32_bf16(a2[0], b1, c0, 0, 0, 0);
            c1 = __builtin_amdgcn_mfma_f32_16x16x32_bf16(a2[1], b1, c1, 0, 0, 0);
            c0 = __builtin_amdgcn_mfma_f32_16x16x32_bf16(a1[0], b2, c0, 0, 0, 0);
            c1 = __builtin_amdgcn_mfma_f32_16x16x32_bf16(a1[1], b2, c1, 0, 0, 0);
            c0 = __builtin_amdgcn_mfma_f32_16x16x32_bf16(a3[0], b1, c0, 0, 0, 0);
            c1 = __builtin_amdgcn_mfma_f32_16x16x32_bf16(a3[1], b1, c1, 0, 0, 0);
            c0 = __builtin_amdgcn_mfma_f32_16x16x32_bf16(a2[0], b2, c0, 0, 0, 0);
            c1 = __builtin_amdgcn_mfma_f32_16x16x32_bf16(a2[1], b2, c1, 0, 0, 0);
            c0 = __builtin_amdgcn_mfma_f32_16x16x32_bf16(a1[0], b3, c0, 0, 0, 0);
            c1 = __builtin_amdgcn_mfma_f32_16x16x32_bf16(a1[1], b3, c1, 0, 0, 0);
            acc[0][ct] = c0; acc[1][ct] = c1;
        }
        // B[cur] ds_reads are consumed by this step's MFMAs before the wave
        // reaches the next barrier -> safe to re-DMA B[cur] at step ks+1.
    }

    // ---- per-token L2 norm from fragments ----
    // C/D layout: col = lane&15 (d), row = (lane>>4)*4 + reg (token within 16)
    float inv_n[2][4];
    #pragma unroll
    for (int rt = 0; rt < 2; ++rt) {
        #pragma unroll
        for (int r = 0; r < 4; ++r) {
            float ss = 0.f;
            #pragma unroll
            for (int ct = 0; ct < 4; ++ct)
                ss = fmaf(acc[rt][ct][r], acc[rt][ct][r], ss);
            ss += __shfl_xor(ss, 1, 64);
            ss += __shfl_xor(ss, 2, 64);
            ss += __shfl_xor(ss, 4, 64);
            ss += __shfl_xor(ss, 8, 64);
            inv_n[rt][r] = 1.0f / fmaxf(sqrtf(ss), 1e-12f);
        }
    }

    __syncthreads();   // all stage-1 LDS traffic done (h_norm overlays it)

    // h_norm -> smem as [d][tok]
    #pragma unroll
    for (int rt = 0; rt < 2; ++rt)
        #pragma unroll
        for (int ct = 0; ct < 4; ++ct)
            #pragma unroll
            for (int r = 0; r < 4; ++r) {
                const int d = ct * 16 + lr;
                const int t = wv * 32 + rt * 16 + lk * 4 + r;
                smem[d * LA + t] = acc[rt][ct][r] * inv_n[rt][r];
            }
    __syncthreads();   // h_norm visible to all

    // ---- stage 2: scores[128][64] = h_norm @ e_norm^T (K=64), fp32 VALU ----
    const int tx = tid & 15;   // cols tx*4 + j
    const int ty = tid >> 4;   // tokens p*64 + ty*4 + i
    float sacc[2][4][4];
    #pragma unroll
    for (int p = 0; p < 2; ++p)
        #pragma unroll
        for (int i = 0; i < 4; ++i)
            #pragma unroll
            for (int j = 0; j < 4; ++j) sacc[p][i][j] = 0.0f;

    #pragma unroll 8
    for (int dd = 0; dd < DE; ++dd) {
        const float* ra = smem + dd * LA;
        float4 a0 = *(const float4*)(ra + ty * 4);
        float4 a1v = *(const float4*)(ra + 64 + ty * 4);
        float4 b  = *(const float4*)(enorm + dd * 64 + tx * 4);
        float av[2][4] = {{a0.x, a0.y, a0.z, a0.w}, {a1v.x, a1v.y, a1v.z, a1v.w}};
        float bv[4] = {b.x, b.y, b.z, b.w};
        #pragma unroll
        for (int p = 0; p < 2; ++p)
            #pragma unroll
            for (int i = 0; i < 4; ++i)
                #pragma unroll
                for (int j = 0; j < 4; ++j)
                    sacc[p][i][j] = fmaf(av[p][i], bv[j], sacc[p][i][j]);
    }

    // ---- epilogue: softmax, top-2, outputs ----
    const float inv_tau = 1.0f / tau_p[0];
    float* outS = out;                        // sparse_gates [NT][64]
    float* outI = out + (size_t)NT * 64;      // topk_indices [NT][2] (as float)
    float* outF = out + (size_t)NT * 66;      // full_gates   [NT][64]

    #pragma unroll
    for (int p = 0; p < 2; ++p) {
        #pragma unroll
        for (int i = 0; i < 4; ++i) {
            const long tok = tok0 + p * 64 + ty * 4 + i;
            float s[4];
            #pragma unroll
            for (int j = 0; j < 4; ++j) s[j] = sacc[p][i][j] * inv_tau;

            float m = fmaxf(fmaxf(s[0], s[1]), fmaxf(s[2], s[3]));
            m = fmaxf(m, __shfl_xor(m, 1, 64));
            m = fmaxf(m, __shfl_xor(m, 2, 64));
            m = fmaxf(m, __shfl_xor(m, 4, 64));
            m = fmaxf(m, __shfl_xor(m, 8, 64));

            float g[4], z = 0.f;
            #pragma unroll
            for (int j = 0; j < 4; ++j) { g[j] = __expf(s[j] - m); z += g[j]; }
            z += __shfl_xor(z, 1, 64);
            z += __shfl_xor(z, 2, 64);
            z += __shfl_xor(z, 4, 64);
            z += __shfl_xor(z, 8, 64);
            const float invZ = 1.0f / z;

            *(float4*)(outF + tok * 64 + tx * 4) =
                make_float4(g[0] * invZ, g[1] * invZ, g[2] * invZ, g[3] * invZ);

            // top-2 on s (monotone with gates); ties -> lower index (jax top_k)
            float v1 = -3.4e38f, v2 = -3.4e38f;
            int i1 = 1 << 20, i2 = 1 << 20;
            #pragma unroll
            for (int j = 0; j < 4; ++j) {
                float v = s[j];
                int e = tx * 4 + j;
                if (v > v1 || (v == v1 && e < i1)) { v2 = v1; i2 = i1; v1 = v; i1 = e; }
                else if (v > v2 || (v == v2 && e < i2)) { v2 = v; i2 = e; }
            }
            #pragma unroll
            for (int msk = 1; msk <= 8; msk <<= 1) {
                float o1 = __shfl_xor(v1, msk, 64); int oi1 = __shfl_xor(i1, msk, 64);
                float o2 = __shfl_xor(v2, msk, 64); int oi2 = __shfl_xor(i2, msk, 64);
                if (o1 > v1 || (o1 == v1 && oi1 < i1)) {
                    if (v1 > o2 || (v1 == o2 && i1 < oi2)) { v2 = v1; i2 = i1; }
                    else { v2 = o2; i2 = oi2; }
                    v1 = o1; i1 = oi1;
                } else {
                    if (o1 > v2 || (o1 == v2 && oi1 < i2)) { v2 = o1; i2 = oi1; }
                }
            }

            // softmax over the two top GATE values
            float gv1 = __expf(v1 - m) * invZ;
            float gv2 = __expf(v2 - m) * invZ;
            float qq = __expf(gv2 - gv1);
            float w1 = 1.0f / (1.0f + qq);
            float w2 = qq * w1;

            float sp[4];
            #pragma unroll
            for (int j = 0; j < 4; ++j) {
                int e = tx * 4 + j;
                sp[j] = (e == i1) ? w1 : ((e == i2) ? w2 : 0.0f);
            }
            *(float4*)(outS + tok * 64 + tx * 4) = make_float4(sp[0], sp[1], sp[2], sp[3]);
            if (tx == 0) {
                *(float2*)(outI + tok * 2) = make_float2((float)i1, (float)i2);
            }
        }
    }
#undef STAGE_A
#undef STAGE_B
}

extern "C" void kernel_launch(void* const* d_in, const int* in_sizes, int n_in,
                              void* d_out, int out_size, void* d_ws, size_t ws_size,
                              hipStream_t stream) {
    const float* h   = (const float*)d_in[0];
    const float* W   = (const float*)d_in[1];
    const float* E   = (const float*)d_in[2];
    const float* tau = (const float*)d_in[3];
    float* out = (float*)d_out;
    unsigned int* ws = (unsigned int*)d_ws;   // 192KB W frags + 16KB e_norm^T

    prep<<<17, 256, 0, stream>>>(W, E, ws);
    moe_all<<<NT / BM, 256, 0, stream>>>(h, ws, (const float*)(ws + WS_EN), tau, out);
}